// Round 9
// baseline (378.524 us; speedup 1.0000x reference)
//
#include <hip/hip_runtime.h>
#include <hip/hip_bf16.h>

typedef unsigned short u16;
typedef unsigned int u32;
typedef float floatx4 __attribute__((ext_vector_type(4)));
typedef __bf16 bf16x8 __attribute__((ext_vector_type(8)));
typedef u16 ushort4v __attribute__((ext_vector_type(4)));
typedef u16 ushort8v __attribute__((ext_vector_type(8)));

#define DEVI static __device__ __forceinline__

DEVI u16 f2bf(float f) {
    u32 u = __builtin_bit_cast(u32, f);
    u += 0x7fffu + ((u >> 16) & 1u);   // round-to-nearest-even
    return (u16)(u >> 16);
}
DEVI float bf2f(u16 h) { return __builtin_bit_cast(float, (u32)h << 16); }

DEVI float fexp2(float x) { return __builtin_amdgcn_exp2f(x); }  // v_exp_f32

// async global->LDS, 16B per lane. dst must be wave-uniform base; HW adds lane*16.
DEVI void async_cp16(const u16* g, u16* l) {
    __builtin_amdgcn_global_load_lds((const __attribute__((address_space(1))) u32*)g,
                                     (__attribute__((address_space(3))) u32*)l, 16, 0, 0);
}

// ---------------------------------------------------------------------------
// GEMM: C[M,N] = A[M,K](bf16) @ W[N,K](bf16)^T, double-buffered one-barrier
// K-loop, async global_load_lds staging with XOR swizzle.
// ---------------------------------------------------------------------------
template<int BM, int BN, int RW, int CW, bool QKV3, bool SPLITK,
         bool BIAS, bool RELU, bool RESID, bool OBF16>
__global__ __launch_bounds__(256) void gemm_nt(
    const u16* __restrict__ A,
    const u16* __restrict__ W0, const u16* __restrict__ W1, const u16* __restrict__ W2,
    const float* __restrict__ bias, const float* __restrict__ resid,
    void* __restrict__ o0, void* __restrict__ o1, void* __restrict__ o2,
    int K, int lda, int Nper, int NX)
{
    static_assert(RW * CW == 4, "4 waves");
    constexpr int WM = BM / RW, WN = BN / CW;
    constexpr int MI = WM / 16, NI = WN / 16;
    __shared__ __align__(16) u16 As[2][BM * 32];
    __shared__ __align__(16) u16 Bs[2][BN * 32];
    const int tid = threadIdx.x;
    const int w = tid >> 6, lane = tid & 63;
    const int q = lane >> 4, ml = lane & 15;
    const int wr = w / CW, wc = w % CW;
    const int m0 = blockIdx.y * BM;
    int bx = blockIdx.x;
    size_t kbase = 0;
    int half = 0;
    if (SPLITK) { half = bx / NX; bx -= half * NX; kbase = (size_t)half * K; }
    int n0 = bx * BN;
    const u16* W = W0;
    void* outp = o0;
    if (QKV3) {
        int sel = n0 / Nper;
        n0 -= sel * Nper;
        W = (sel == 0) ? W0 : (sel == 1 ? W1 : W2);
        outp = (sel == 0) ? o0 : (sel == 1 ? o1 : o2);
    }
    if (SPLITK) outp = half ? o1 : o0;

    auto stage = [&](int buf, int kt) {
#pragma unroll
        for (int p = 0; p < BM / 64; ++p) {
            int g = p * 256 + tid;
            int r = g >> 2, s = g & 3;
            int c = s ^ ((r >> 1) & 3);
            async_cp16(A + (size_t)(m0 + r) * lda + kbase + kt + c * 8,
                       &As[buf][(p * 256 + w * 64) * 8]);
        }
#pragma unroll
        for (int p = 0; p < BN / 64; ++p) {
            int g = p * 256 + tid;
            int r = g >> 2, s = g & 3;
            int c = s ^ ((r >> 1) & 3);
            async_cp16(W + (size_t)(n0 + r) * lda + kbase + kt + c * 8,
                       &Bs[buf][(p * 256 + w * 64) * 8]);
        }
    };

    const floatx4 fzero = {0.f, 0.f, 0.f, 0.f};
    floatx4 acc[MI][NI];
#pragma unroll
    for (int i = 0; i < MI; ++i)
#pragma unroll
        for (int j = 0; j < NI; ++j) acc[i][j] = fzero;

    stage(0, 0);
    for (int it = 0, kt = 0; kt < K; ++it, kt += 32) {
        __syncthreads();
        if (kt + 32 < K) stage((it + 1) & 1, kt + 32);
        const u16* Asb = As[it & 1];
        const u16* Bsb = Bs[it & 1];
        bf16x8 af[MI], bfr[NI];
#pragma unroll
        for (int i = 0; i < MI; ++i) {
            int rm = wr * WM + i * 16 + ml;
            int s = q ^ ((rm >> 1) & 3);
            af[i] = *(const bf16x8*)&Asb[(rm * 4 + s) * 8];
        }
#pragma unroll
        for (int j = 0; j < NI; ++j) {
            int rn = wc * WN + j * 16 + ml;
            int s = q ^ ((rn >> 1) & 3);
            bfr[j] = *(const bf16x8*)&Bsb[(rn * 4 + s) * 8];
        }
#pragma unroll
        for (int i = 0; i < MI; ++i)
#pragma unroll
            for (int j = 0; j < NI; ++j)
                acc[i][j] = __builtin_amdgcn_mfma_f32_16x16x32_bf16(af[i], bfr[j], acc[i][j], 0, 0, 0);
    }

    // epilogue: C/D layout col=lane&15, row=(lane>>4)*4+reg
#pragma unroll
    for (int j = 0; j < NI; ++j) {
        int gn = n0 + wc * WN + j * 16 + ml;
        float bj = 0.f;
        if (BIAS) bj = bias[gn];
#pragma unroll
        for (int i = 0; i < MI; ++i) {
            int gm0 = m0 + wr * WM + i * 16 + q * 4;
#pragma unroll
            for (int r = 0; r < 4; ++r) {
                size_t idx = (size_t)(gm0 + r) * Nper + gn;
                float v = acc[i][j][r] + bj;
                if (RELU) v = fmaxf(v, 0.f);
                if (RESID) v += resid[idx];
                if (OBF16) ((u16*)outp)[idx] = f2bf(v);
                else       ((float*)outp)[idx] = v;
            }
        }
    }
}

// ---------------------------------------------------------------------------
// Flash attention v8: flash7 + key-range split (linear softmax: no max term,
// so partial Sum(p*V) and Sum(p) over key halves just add). grid.z=2 halves
// of 1024 keys (16 iters) -> 2048 blocks total for occupancy/ramp.
// Partials stored bf16 (error ~0.4% of partial, inside tolerance), combined
// by attn_fin with 1/(l0+l1). Everything else = flash7 (transposed-S,
// key-relabeled PV at 16x16x32, zero P LDS traffic, conflict-free swizzle).
// ---------------------------------------------------------------------------
__global__ __launch_bounds__(128, 2) void flash8(
    const u16* __restrict__ Q, const u16* __restrict__ Kg,
    const u16* __restrict__ Vt, const float* __restrict__ biasv,
    u16* __restrict__ O0, u16* __restrict__ O1, float* __restrict__ Lp)
{
    __shared__ __align__(16) u16 Ks[2][64 * 64];
    __shared__ __align__(16) u16 Vs[2][64 * 64];
    const int tid = threadIdx.x;
    const int w = tid >> 6, lane = tid & 63;
    const int q = lane >> 4, ml = lane & 15;
    const int b = blockIdx.y >> 4, h = blockIdx.y & 15;
    const int half = blockIdx.z;
    const int kb = half * 1024;
    const size_t rowQ = (size_t)(b * 2048 + blockIdx.x * 64);
    const float KSC = 0.125f * 1.4426950408889634f;   // /sqrt(64) * log2(e)
    const floatx4 fzero = {0.f, 0.f, 0.f, 0.f};

    // Q B-fragments: query = w*32 + qg*16 + ml, d = q*8+j + c*32
    bf16x8 qa[2][2];
#pragma unroll
    for (int qg = 0; qg < 2; ++qg)
#pragma unroll
        for (int c = 0; c < 2; ++c)
            qa[qg][c] = *(const bf16x8*)&Q[(rowQ + w * 32 + qg * 16 + ml) * 1024
                                           + h * 64 + q * 8 + c * 32];

    auto stage = [&](int buf, int s0) {
#pragma unroll
        for (int p = 0; p < 4; ++p) {
            int L = p * 128 + tid;
            int row = L >> 3, sl = L & 7;
            int ch = sl ^ ((row & 3) | (((row >> 3) & 1) << 2));
            async_cp16(Kg + (size_t)(b * 2048 + s0 + row) * 1024 + h * 64 + ch * 8,
                       &Ks[buf][(p * 128 + w * 64) * 8]);
            async_cp16(Vt + (size_t)(b * 1024 + h * 64 + row) * 2048 + s0 + ch * 8,
                       &Vs[buf][(p * 128 + w * 64) * 8]);
        }
    };

    floatx4 oacc[2][4];          // [qg][dt]: lane = (d=dt*16+q*4+r, query=ml)
    float lsum[2] = {0.f, 0.f};
#pragma unroll
    for (int qg = 0; qg < 2; ++qg)
#pragma unroll
        for (int d = 0; d < 4; ++d) oacc[qg][d] = fzero;

    const int swk = (ml & 3) | (((ml >> 2) & 1) << 2);
    const int swv = (ml & 3) | (((ml >> 3) & 1) << 2);

    stage(0, kb);
    for (int it = 0; it < 16; ++it) {
        __syncthreads();
        if (it + 1 < 16) stage((it + 1) & 1, kb + (it + 1) * 64);
        const u16* Kb = Ks[it & 1];
        const u16* Vb = Vs[it & 1];
        const int s0 = kb + it * 64;

        bf16x8 pfrag[2][2];   // [g][qg]
#pragma unroll
        for (int g = 0; g < 2; ++g) {
            const int re = g * 32 + ((ml >> 2) << 3) + (ml & 3);  // even rows
            bf16x8 ke0 = *(const bf16x8*)&Kb[(re + 0) * 64 + ((0 + q) ^ swk) * 8];
            bf16x8 ke1 = *(const bf16x8*)&Kb[(re + 0) * 64 + ((4 + q) ^ swk) * 8];
            bf16x8 ko0 = *(const bf16x8*)&Kb[(re + 4) * 64 + ((0 + q) ^ swk) * 8];
            bf16x8 ko1 = *(const bf16x8*)&Kb[(re + 4) * 64 + ((4 + q) ^ swk) * 8];
            const float4 be = *(const float4*)&biasv[b * 2048 + s0 + g * 32 + q * 8];
            const float4 bo = *(const float4*)&biasv[b * 2048 + s0 + g * 32 + q * 8 + 4];
#pragma unroll
            for (int qg = 0; qg < 2; ++qg) {
                floatx4 te = fzero, to = fzero;
                te = __builtin_amdgcn_mfma_f32_16x16x32_bf16(ke0, qa[qg][0], te, 0, 0, 0);
                te = __builtin_amdgcn_mfma_f32_16x16x32_bf16(ke1, qa[qg][1], te, 0, 0, 0);
                to = __builtin_amdgcn_mfma_f32_16x16x32_bf16(ko0, qa[qg][0], to, 0, 0, 0);
                to = __builtin_amdgcn_mfma_f32_16x16x32_bf16(ko1, qa[qg][1], to, 0, 0, 0);
                float pe0 = fexp2(fmaf(te[0], KSC, be.x));
                float pe1 = fexp2(fmaf(te[1], KSC, be.y));
                float pe2 = fexp2(fmaf(te[2], KSC, be.z));
                float pe3 = fexp2(fmaf(te[3], KSC, be.w));
                float po0 = fexp2(fmaf(to[0], KSC, bo.x));
                float po1 = fexp2(fmaf(to[1], KSC, bo.y));
                float po2 = fexp2(fmaf(to[2], KSC, bo.z));
                float po3 = fexp2(fmaf(to[3], KSC, bo.w));
                lsum[qg] += ((pe0 + pe1) + (pe2 + pe3)) + ((po0 + po1) + (po2 + po3));
                u32 pk[4];
                pk[0] = ((__builtin_bit_cast(u32, pe0) + 0x8000u) >> 16)
                      | ((__builtin_bit_cast(u32, pe1) + 0x8000u) & 0xffff0000u);
                pk[1] = ((__builtin_bit_cast(u32, pe2) + 0x8000u) >> 16)
                      | ((__builtin_bit_cast(u32, pe3) + 0x8000u) & 0xffff0000u);
                pk[2] = ((__builtin_bit_cast(u32, po0) + 0x8000u) >> 16)
                      | ((__builtin_bit_cast(u32, po1) + 0x8000u) & 0xffff0000u);
                pk[3] = ((__builtin_bit_cast(u32, po2) + 0x8000u) >> 16)
                      | ((__builtin_bit_cast(u32, po3) + 0x8000u) & 0xffff0000u);
                pfrag[g][qg] = __builtin_bit_cast(bf16x8, *(uint4*)pk);
            }
        }
#pragma unroll
        for (int dt = 0; dt < 4; ++dt) {
            int vrow = dt * 16 + ml;
#pragma unroll
            for (int g = 0; g < 2; ++g) {
                bf16x8 vf = *(const bf16x8*)&Vb[vrow * 64 + ((g * 4 + q) ^ swv) * 8];
#pragma unroll
                for (int qg = 0; qg < 2; ++qg)
                    oacc[qg][dt] = __builtin_amdgcn_mfma_f32_16x16x32_bf16(
                        vf, pfrag[g][qg], oacc[qg][dt], 0, 0, 0);
            }
        }
    }
    u16* Op = half ? O1 : O0;
#pragma unroll
    for (int qg = 0; qg < 2; ++qg) {
        float ls = lsum[qg];
        ls += __shfl_xor(ls, 16, 64);
        ls += __shfl_xor(ls, 32, 64);
        const int qs = blockIdx.x * 64 + w * 32 + qg * 16 + ml;
        if (q == 0)
            Lp[(((half * 2 + b) * 16) + h) * 2048 + qs] = ls;
        const size_t row = rowQ + w * 32 + qg * 16 + ml;
#pragma unroll
        for (int dt = 0; dt < 4; ++dt) {
            u32 pk0 = (u32)f2bf(oacc[qg][dt][0]) | ((u32)f2bf(oacc[qg][dt][1]) << 16);
            u32 pk1 = (u32)f2bf(oacc[qg][dt][2]) | ((u32)f2bf(oacc[qg][dt][3]) << 16);
            u32 pk[2] = {pk0, pk1};
            *(ushort4v*)&Op[row * 1024 + h * 64 + dt * 16 + q * 4] =
                __builtin_bit_cast(ushort4v, *(ulong1*)pk);
        }
    }
}

// combine: attn = (O0 + O1) / (l0 + l1), bf16 out
__global__ __launch_bounds__(256) void attn_fin(
    const u16* __restrict__ O0, const u16* __restrict__ O1,
    const float* __restrict__ Lp, u16* __restrict__ attn)
{
    const int row = blockIdx.x;
    const int b = row >> 11, qs = row & 2047;
    const int c0 = threadIdx.x * 4;
    const int h = c0 >> 6;
    float l0 = Lp[((b * 16) + h) * 2048 + qs];
    float l1 = Lp[(((2 + b) * 16) + h) * 2048 + qs];
    float rcp = 1.f / (l0 + l1);
    ushort4v a = *(const ushort4v*)&O0[(size_t)row * 1024 + c0];
    ushort4v bb = *(const ushort4v*)&O1[(size_t)row * 1024 + c0];
    ushort4v o;
#pragma unroll
    for (int i = 0; i < 4; ++i)
        o[i] = f2bf((bf2f(a[i]) + bf2f(bb[i])) * rcp);
    *(ushort4v*)&attn[(size_t)row * 1024 + c0] = o;
}

// V [b*2048+s][h*64+d] -> Vt [b*1024+h*64+d][s], 64x64 tiles via LDS
__global__ __launch_bounds__(256) void vtrans(const u16* __restrict__ Vb, u16* __restrict__ Vt)
{
    __shared__ __align__(16) u16 T[64 * 72];
    const int tid = threadIdx.x;
    const int ct = blockIdx.x, rt = blockIdx.y;
    const int b = rt >> 5;
    const int s0 = (rt & 31) * 64;
    const int c0 = ct * 64;
#pragma unroll
    for (int p = 0; p < 2; ++p) {
        int slot = p * 256 + tid;
        int lr = slot >> 3, pc = slot & 7;
        bf16x8 v = *(const bf16x8*)&Vb[(size_t)(b * 2048 + s0 + lr) * 1024 + c0 + pc * 8];
        *(bf16x8*)&T[lr * 72 + pc * 8] = v;
    }
    __syncthreads();
#pragma unroll
    for (int p = 0; p < 2; ++p) {
        int slot = p * 256 + tid;
        int dc = slot >> 3, sc0 = (slot & 7) * 8;
        ushort8v o;
#pragma unroll
        for (int j = 0; j < 8; ++j) o[j] = T[(sc0 + j) * 72 + dc];
        *(ushort8v*)&Vt[(size_t)(b * 1024 + c0 + dc) * 2048 + s0 + sc0] = o;
    }
}

// LayerNorm (torch semantics: ddof=1 variance, eps added to std), fp32 -> bf16
DEVI void ln_row(const float* __restrict__ x, float ga, float gb,
                 u16* __restrict__ y, int row, int tid)
{
    const float4 v = ((const float4*)(x + (size_t)row * 1024))[tid];
    float s = v.x + v.y + v.z + v.w;
    float ss = v.x * v.x + v.y * v.y + v.z * v.z + v.w * v.w;
#pragma unroll
    for (int d = 1; d < 64; d <<= 1) { s += __shfl_xor(s, d, 64); ss += __shfl_xor(ss, d, 64); }
    __shared__ float ps[4], pss[4];
    const int w = tid >> 6, lane = tid & 63;
    if (lane == 0) { ps[w] = s; pss[w] = ss; }
    __syncthreads();
    s = ps[0] + ps[1] + ps[2] + ps[3];
    ss = pss[0] + pss[1] + pss[2] + pss[3];
    float mean = s * (1.f / 1024.f);
    float var = fmaxf((ss - s * mean) * (1.f / 1023.f), 0.f);
    float sc = ga / (sqrtf(var) + 1e-6f);
    ushort4v o;
    o[0] = f2bf((v.x - mean) * sc + gb);
    o[1] = f2bf((v.y - mean) * sc + gb);
    o[2] = f2bf((v.z - mean) * sc + gb);
    o[3] = f2bf((v.w - mean) * sc + gb);
    ((ushort4v*)(y + (size_t)row * 1024))[tid] = o;
}

__global__ __launch_bounds__(256) void ln_bf16(const float* __restrict__ x,
    const float* __restrict__ ga, const float* __restrict__ gb, u16* __restrict__ y)
{
    ln_row(x, ga[0], gb[0], y, blockIdx.x, threadIdx.x);
}

// prep: weight casts (blocks 0..12287) + mask bias (12288..12303) + LN1 (12304..16399)
__global__ __launch_bounds__(256) void prep(
    const float* __restrict__ wq, const float* __restrict__ wk,
    const float* __restrict__ wv, const float* __restrict__ wo,
    const float* __restrict__ w1, const float* __restrict__ w2,
    u16* __restrict__ wqb, u16* __restrict__ wkb, u16* __restrict__ wvb,
    u16* __restrict__ wob, u16* __restrict__ w1b, u16* __restrict__ w2b,
    const int* __restrict__ m, float* __restrict__ biasv,
    const float* __restrict__ src, const float* __restrict__ a1,
    const float* __restrict__ be1, u16* __restrict__ xln1)
{
    const int bx = blockIdx.x;
    if (bx < 12288) {
        size_t i = (size_t)bx * 256 + threadIdx.x;   // float4 index
        const float* s; u16* d; size_t off;
        if (i < 262144)       { s = wq; d = wqb; off = i; }
        else if (i < 524288)  { s = wk; d = wkb; off = i - 262144; }
        else if (i < 786432)  { s = wv; d = wvb; off = i - 524288; }
        else if (i < 1048576) { s = wo; d = wob; off = i - 786432; }
        else if (i < 2097152) { s = w1; d = w1b; off = i - 1048576; }
        else                  { s = w2; d = w2b; off = i - 2097152; }
        float4 v = ((const float4*)s)[off];
        ushort4v o = {f2bf(v.x), f2bf(v.y), f2bf(v.z), f2bf(v.w)};
        ((ushort4v*)d)[off] = o;
    } else if (bx < 12304) {
        int i = (bx - 12288) * 256 + threadIdx.x;
        biasv[i] = m[i] ? 0.f : -1.442695e9f;
    } else {
        ln_row(src, a1[0], be1[0], xln1, bx - 12304, threadIdx.x);
    }
}

// FF2 finish: out = P0 + P1 + b2[col] + resid
__global__ __launch_bounds__(256) void ff2_fin(const float* __restrict__ p0, const float* __restrict__ p1,
    const float* __restrict__ b2, const float* __restrict__ resid, float* __restrict__ out)
{
    const size_t i = (size_t)blockIdx.x * 256 + threadIdx.x;   // float4 index
    float4 a = ((const float4*)p0)[i];
    float4 b = ((const float4*)p1)[i];
    float4 r = ((const float4*)resid)[i];
    float4 bb = ((const float4*)b2)[i & 255];
    float4 o = {a.x + b.x + r.x + bb.x, a.y + b.y + r.y + bb.y,
                a.z + b.z + r.z + bb.z, a.w + b.w + r.w + bb.w};
    ((float4*)out)[i] = o;
}

extern "C" void kernel_launch(void* const* d_in, const int* in_sizes, int n_in,
                              void* d_out, int out_size, void* d_ws, size_t ws_size,
                              hipStream_t stream)
{
    const float* src = (const float*)d_in[0];
    const int* msk   = (const int*)d_in[1];
    const float* wq  = (const float*)d_in[2];
    const float* wk  = (const float*)d_in[3];
    const float* wv  = (const float*)d_in[4];
    const float* wo  = (const float*)d_in[5];
    const float* w1  = (const float*)d_in[6];
    const float* b1  = (const float*)d_in[7];
    const float* w2  = (const float*)d_in[8];
    const float* b2  = (const float*)d_in[9];
    const float* a1  = (const float*)d_in[10];
    const float* be1 = (const float*)d_in[11];
    const float* a2  = (const float*)d_in[12];
    const float* be2 = (const float*)d_in[13];
    float* out = (float*)d_out;

    char* ws = (char*)d_ws;
    const size_t MB = (size_t)1 << 20;
    u16* wqb  = (u16*)(ws + 0 * MB);
    u16* wkb  = (u16*)(ws + 2 * MB);
    u16* wvb  = (u16*)(ws + 4 * MB);
    u16* wob  = (u16*)(ws + 6 * MB);
    u16* w1b  = (u16*)(ws + 8 * MB);    // 8..16
    u16* w2b  = (u16*)(ws + 16 * MB);   // 16..24
    u16* xln1 = (u16*)(ws + 24 * MB);   // 24..32; dead after QKV; aliased by attn
    u16* attn = xln1;
    u16* Qb   = (u16*)(ws + 32 * MB);   // 32..40; dead after flash; aliased by xln2
    u16* xln2 = Qb;
    u16* Kb   = (u16*)(ws + 40 * MB);   // 40..48
    u16* Vb   = (u16*)(ws + 48 * MB);   // 48..56; dead after vtrans -> Oh0
    u16* Vt   = (u16*)(ws + 56 * MB);   // 56..64
    float* biasv = (float*)(ws + 64 * MB);  // 16 KB in 64..72 spare
    u16* h1   = (u16*)(ws + 40 * MB);   // 32 MB: 40..72 (Kb/Vb/Vt dead by then)
    float* src2 = (float*)(ws + 72 * MB); // 16 MB: 72..88 (written after attn_fin)
    u16* Oh0  = (u16*)(ws + 48 * MB);   // 8 MB bf16 partial (Vb dead during flash)
    u16* Oh1  = (u16*)(ws + 72 * MB);   // 8 MB (src2 region, dead during flash)
    float* Lp = (float*)(ws + 80 * MB); // 512 KB lsum partials (dead before oproj)
    float* P0 = (float*)(ws + 0 * MB);   // 0..16  (weight casts dead by FF2)
    float* P1 = (float*)(ws + 24 * MB);  // 24..40 (attn/xln2 dead by FF2)

    // fused: weight casts + mask bias + LN1
    prep<<<16400, 256, 0, stream>>>(wq, wk, wv, wo, w1, w2,
                                    wqb, wkb, wvb, wob, w1b, w2b,
                                    msk, biasv, src, a1, be1, xln1);

    // fused QKV: N_total=3072, per-block weight/output select
    gemm_nt<128, 128, 2, 2, true, false, false, false, false, true><<<dim3(24, 32), 256, 0, stream>>>(
        xln1, wqb, wkb, wvb, nullptr, nullptr, Qb, Kb, Vb, 1024, 1024, 1024, 0);

    vtrans<<<dim3(16, 64), 256, 0, stream>>>(Vb, Vt);

    // key-split flash: z = key half
    flash8<<<dim3(32, 32, 2), 128, 0, stream>>>(Qb, Kb, Vt, biasv, Oh0, Oh1, Lp);
    attn_fin<<<4096, 256, 0, stream>>>(Oh0, Oh1, Lp, attn);

    // O-projection + residual (fp32)
    gemm_nt<128, 64, 4, 1, false, false, false, false, true, false><<<dim3(16, 32), 256, 0, stream>>>(
        attn, wob, nullptr, nullptr, nullptr, src, src2, nullptr, nullptr, 1024, 1024, 1024, 0);

    ln_bf16<<<4096, 256, 0, stream>>>(src2, a2, be2, xln2);

    // FF1: bias + ReLU -> bf16
    gemm_nt<128, 128, 2, 2, false, false, true, true, false, true><<<dim3(32, 32), 256, 0, stream>>>(
        xln2, w1b, nullptr, nullptr, b1, nullptr, h1, nullptr, nullptr, 1024, 1024, 4096, 0);

    // FF2: split-K=2 into fp32 partials
    gemm_nt<128, 128, 2, 2, false, true, false, false, false, false><<<dim3(16, 32), 256, 0, stream>>>(
        h1, w2b, nullptr, nullptr, nullptr, nullptr, P0, P1, nullptr, 2048, 4096, 1024, 8);

    // out = P0 + P1 + b2 + src2
    ff2_fin<<<4096, 256, 0, stream>>>(P0, P1, b2, src2, out);
}

// Round 10
// 368.963 us; speedup vs baseline: 1.0259x; 1.0259x over previous
//
#include <hip/hip_runtime.h>
#include <hip/hip_bf16.h>

typedef unsigned short u16;
typedef unsigned int u32;
typedef float floatx4 __attribute__((ext_vector_type(4)));
typedef __bf16 bf16x8 __attribute__((ext_vector_type(8)));
typedef u16 ushort4v __attribute__((ext_vector_type(4)));
typedef u16 ushort8v __attribute__((ext_vector_type(8)));

#define DEVI static __device__ __forceinline__

DEVI u16 f2bf(float f) {
    u32 u = __builtin_bit_cast(u32, f);
    u += 0x7fffu + ((u >> 16) & 1u);   // round-to-nearest-even
    return (u16)(u >> 16);
}
DEVI float bf2f(u16 h) { return __builtin_bit_cast(float, (u32)h << 16); }

DEVI float fexp2(float x) { return __builtin_amdgcn_exp2f(x); }  // v_exp_f32

// async global->LDS, 16B per lane. dst must be wave-uniform base; HW adds lane*16.
DEVI void async_cp16(const u16* g, u16* l) {
    __builtin_amdgcn_global_load_lds((const __attribute__((address_space(1))) u32*)g,
                                     (__attribute__((address_space(3))) u32*)l, 16, 0, 0);
}

// ---------------------------------------------------------------------------
// GEMM: C[M,N] = A[M,K](bf16) @ W[N,K](bf16)^T, double-buffered one-barrier
// K-loop, async global_load_lds staging with XOR swizzle.
// NSPLIT>1: grid.x = NX*NSPLIT; part = bx/NX works K-range [part*K, part*K+K)
// of rows with stride lda, writing partials to o0..o3.
// ---------------------------------------------------------------------------
template<int BM, int BN, int RW, int CW, bool QKV3, int NSPLIT,
         bool BIAS, bool RELU, bool RESID, bool OBF16>
__global__ __launch_bounds__(256) void gemm_nt(
    const u16* __restrict__ A,
    const u16* __restrict__ W0, const u16* __restrict__ W1, const u16* __restrict__ W2,
    const float* __restrict__ bias, const float* __restrict__ resid,
    void* __restrict__ o0, void* __restrict__ o1, void* __restrict__ o2,
    void* __restrict__ o3, int K, int lda, int Nper, int NX)
{
    static_assert(RW * CW == 4, "4 waves");
    constexpr int WM = BM / RW, WN = BN / CW;
    constexpr int MI = WM / 16, NI = WN / 16;
    __shared__ __align__(16) u16 As[2][BM * 32];
    __shared__ __align__(16) u16 Bs[2][BN * 32];
    const int tid = threadIdx.x;
    const int w = tid >> 6, lane = tid & 63;
    const int q = lane >> 4, ml = lane & 15;
    const int wr = w / CW, wc = w % CW;
    const int m0 = blockIdx.y * BM;
    int bx = blockIdx.x;
    size_t kbase = 0;
    const u16* W = W0;
    void* outp = o0;
    if (NSPLIT > 1) {
        int part = bx / NX; bx -= part * NX; kbase = (size_t)part * K;
        outp = (part == 0) ? o0 : (part == 1 ? o1 : (part == 2 ? o2 : o3));
    }
    int n0 = bx * BN;
    if (QKV3) {
        int sel = n0 / Nper;
        n0 -= sel * Nper;
        W = (sel == 0) ? W0 : (sel == 1 ? W1 : W2);
        outp = (sel == 0) ? o0 : (sel == 1 ? o1 : o2);
    }

    auto stage = [&](int buf, int kt) {
#pragma unroll
        for (int p = 0; p < BM / 64; ++p) {
            int g = p * 256 + tid;
            int r = g >> 2, s = g & 3;
            int c = s ^ ((r >> 1) & 3);
            async_cp16(A + (size_t)(m0 + r) * lda + kbase + kt + c * 8,
                       &As[buf][(p * 256 + w * 64) * 8]);
        }
#pragma unroll
        for (int p = 0; p < BN / 64; ++p) {
            int g = p * 256 + tid;
            int r = g >> 2, s = g & 3;
            int c = s ^ ((r >> 1) & 3);
            async_cp16(W + (size_t)(n0 + r) * lda + kbase + kt + c * 8,
                       &Bs[buf][(p * 256 + w * 64) * 8]);
        }
    };

    const floatx4 fzero = {0.f, 0.f, 0.f, 0.f};
    floatx4 acc[MI][NI];
#pragma unroll
    for (int i = 0; i < MI; ++i)
#pragma unroll
        for (int j = 0; j < NI; ++j) acc[i][j] = fzero;

    stage(0, 0);
    for (int it = 0, kt = 0; kt < K; ++it, kt += 32) {
        __syncthreads();
        if (kt + 32 < K) stage((it + 1) & 1, kt + 32);
        const u16* Asb = As[it & 1];
        const u16* Bsb = Bs[it & 1];
        bf16x8 af[MI], bfr[NI];
#pragma unroll
        for (int i = 0; i < MI; ++i) {
            int rm = wr * WM + i * 16 + ml;
            int s = q ^ ((rm >> 1) & 3);
            af[i] = *(const bf16x8*)&Asb[(rm * 4 + s) * 8];
        }
#pragma unroll
        for (int j = 0; j < NI; ++j) {
            int rn = wc * WN + j * 16 + ml;
            int s = q ^ ((rn >> 1) & 3);
            bfr[j] = *(const bf16x8*)&Bsb[(rn * 4 + s) * 8];
        }
#pragma unroll
        for (int i = 0; i < MI; ++i)
#pragma unroll
            for (int j = 0; j < NI; ++j)
                acc[i][j] = __builtin_amdgcn_mfma_f32_16x16x32_bf16(af[i], bfr[j], acc[i][j], 0, 0, 0);
    }

    // epilogue: C/D layout col=lane&15, row=(lane>>4)*4+reg
#pragma unroll
    for (int j = 0; j < NI; ++j) {
        int gn = n0 + wc * WN + j * 16 + ml;
        float bj = 0.f;
        if (BIAS) bj = bias[gn];
#pragma unroll
        for (int i = 0; i < MI; ++i) {
            int gm0 = m0 + wr * WM + i * 16 + q * 4;
#pragma unroll
            for (int r = 0; r < 4; ++r) {
                size_t idx = (size_t)(gm0 + r) * Nper + gn;
                float v = acc[i][j][r] + bj;
                if (RELU) v = fmaxf(v, 0.f);
                if (RESID) v += resid[idx];
                if (OBF16) ((u16*)outp)[idx] = f2bf(v);
                else       ((float*)outp)[idx] = v;
            }
        }
    }
}

// ---------------------------------------------------------------------------
// Flash attention v7 (restored R8 winner): transposed-S + key-relabeled S^T so
// PV runs at 16x16x32. Block = 128 threads (2 waves) x 32 queries = 64 queries.
// Zero P LDS traffic, conflict-free swizzle, per-lane lsum, 2 shuffles total.
// Q,K: [b*2048+s][h*64+d].  Vt: [b*1024+h*64+d][s].
// ---------------------------------------------------------------------------
__global__ __launch_bounds__(128, 2) void flash7(
    const u16* __restrict__ Q, const u16* __restrict__ Kg,
    const u16* __restrict__ Vt, const float* __restrict__ biasv,
    u16* __restrict__ O)
{
    __shared__ __align__(16) u16 Ks[2][64 * 64];
    __shared__ __align__(16) u16 Vs[2][64 * 64];
    const int tid = threadIdx.x;
    const int w = tid >> 6, lane = tid & 63;
    const int q = lane >> 4, ml = lane & 15;
    const int b = blockIdx.y >> 4, h = blockIdx.y & 15;
    const size_t rowQ = (size_t)(b * 2048 + blockIdx.x * 64);
    const float KSC = 0.125f * 1.4426950408889634f;   // /sqrt(64) * log2(e)
    const floatx4 fzero = {0.f, 0.f, 0.f, 0.f};

    // Q B-fragments: query = w*32 + qg*16 + ml, d = q*8+j + c*32
    bf16x8 qa[2][2];
#pragma unroll
    for (int qg = 0; qg < 2; ++qg)
#pragma unroll
        for (int c = 0; c < 2; ++c)
            qa[qg][c] = *(const bf16x8*)&Q[(rowQ + w * 32 + qg * 16 + ml) * 1024
                                           + h * 64 + q * 8 + c * 32];

    auto stage = [&](int buf, int s0) {
#pragma unroll
        for (int p = 0; p < 4; ++p) {
            int L = p * 128 + tid;
            int row = L >> 3, sl = L & 7;
            int ch = sl ^ ((row & 3) | (((row >> 3) & 1) << 2));
            async_cp16(Kg + (size_t)(b * 2048 + s0 + row) * 1024 + h * 64 + ch * 8,
                       &Ks[buf][(p * 128 + w * 64) * 8]);
            async_cp16(Vt + (size_t)(b * 1024 + h * 64 + row) * 2048 + s0 + ch * 8,
                       &Vs[buf][(p * 128 + w * 64) * 8]);
        }
    };

    floatx4 oacc[2][4];          // [qg][dt]: lane = (d=dt*16+q*4+r, query=ml)
    float lsum[2] = {0.f, 0.f};
#pragma unroll
    for (int qg = 0; qg < 2; ++qg)
#pragma unroll
        for (int d = 0; d < 4; ++d) oacc[qg][d] = fzero;

    const int swk = (ml & 3) | (((ml >> 2) & 1) << 2);
    const int swv = (ml & 3) | (((ml >> 3) & 1) << 2);

    stage(0, 0);
    for (int it = 0; it < 32; ++it) {
        __syncthreads();
        if (it + 1 < 32) stage((it + 1) & 1, (it + 1) * 64);
        const u16* Kb = Ks[it & 1];
        const u16* Vb = Vs[it & 1];
        const int s0 = it * 64;

        bf16x8 pfrag[2][2];   // [g][qg]
#pragma unroll
        for (int g = 0; g < 2; ++g) {
            const int re = g * 32 + ((ml >> 2) << 3) + (ml & 3);  // even rows
            bf16x8 ke0 = *(const bf16x8*)&Kb[(re + 0) * 64 + ((0 + q) ^ swk) * 8];
            bf16x8 ke1 = *(const bf16x8*)&Kb[(re + 0) * 64 + ((4 + q) ^ swk) * 8];
            bf16x8 ko0 = *(const bf16x8*)&Kb[(re + 4) * 64 + ((0 + q) ^ swk) * 8];
            bf16x8 ko1 = *(const bf16x8*)&Kb[(re + 4) * 64 + ((4 + q) ^ swk) * 8];
            const float4 be = *(const float4*)&biasv[b * 2048 + s0 + g * 32 + q * 8];
            const float4 bo = *(const float4*)&biasv[b * 2048 + s0 + g * 32 + q * 8 + 4];
#pragma unroll
            for (int qg = 0; qg < 2; ++qg) {
                floatx4 te = fzero, to = fzero;
                te = __builtin_amdgcn_mfma_f32_16x16x32_bf16(ke0, qa[qg][0], te, 0, 0, 0);
                te = __builtin_amdgcn_mfma_f32_16x16x32_bf16(ke1, qa[qg][1], te, 0, 0, 0);
                to = __builtin_amdgcn_mfma_f32_16x16x32_bf16(ko0, qa[qg][0], to, 0, 0, 0);
                to = __builtin_amdgcn_mfma_f32_16x16x32_bf16(ko1, qa[qg][1], to, 0, 0, 0);
                float pe0 = fexp2(fmaf(te[0], KSC, be.x));
                float pe1 = fexp2(fmaf(te[1], KSC, be.y));
                float pe2 = fexp2(fmaf(te[2], KSC, be.z));
                float pe3 = fexp2(fmaf(te[3], KSC, be.w));
                float po0 = fexp2(fmaf(to[0], KSC, bo.x));
                float po1 = fexp2(fmaf(to[1], KSC, bo.y));
                float po2 = fexp2(fmaf(to[2], KSC, bo.z));
                float po3 = fexp2(fmaf(to[3], KSC, bo.w));
                lsum[qg] += ((pe0 + pe1) + (pe2 + pe3)) + ((po0 + po1) + (po2 + po3));
                u32 pk[4];
                pk[0] = ((__builtin_bit_cast(u32, pe0) + 0x8000u) >> 16)
                      | ((__builtin_bit_cast(u32, pe1) + 0x8000u) & 0xffff0000u);
                pk[1] = ((__builtin_bit_cast(u32, pe2) + 0x8000u) >> 16)
                      | ((__builtin_bit_cast(u32, pe3) + 0x8000u) & 0xffff0000u);
                pk[2] = ((__builtin_bit_cast(u32, po0) + 0x8000u) >> 16)
                      | ((__builtin_bit_cast(u32, po1) + 0x8000u) & 0xffff0000u);
                pk[3] = ((__builtin_bit_cast(u32, po2) + 0x8000u) >> 16)
                      | ((__builtin_bit_cast(u32, po3) + 0x8000u) & 0xffff0000u);
                pfrag[g][qg] = __builtin_bit_cast(bf16x8, *(uint4*)pk);
            }
        }
#pragma unroll
        for (int dt = 0; dt < 4; ++dt) {
            int vrow = dt * 16 + ml;
#pragma unroll
            for (int g = 0; g < 2; ++g) {
                bf16x8 vf = *(const bf16x8*)&Vb[vrow * 64 + ((g * 4 + q) ^ swv) * 8];
#pragma unroll
                for (int qg = 0; qg < 2; ++qg)
                    oacc[qg][dt] = __builtin_amdgcn_mfma_f32_16x16x32_bf16(
                        vf, pfrag[g][qg], oacc[qg][dt], 0, 0, 0);
            }
        }
    }
#pragma unroll
    for (int qg = 0; qg < 2; ++qg) {
        float ls = lsum[qg];
        ls += __shfl_xor(ls, 16, 64);
        ls += __shfl_xor(ls, 32, 64);
        const float rcp = 1.f / ls;
        const size_t row = rowQ + w * 32 + qg * 16 + ml;
#pragma unroll
        for (int dt = 0; dt < 4; ++dt)
#pragma unroll
            for (int rp = 0; rp < 4; rp += 2) {
                u32 pk = (u32)f2bf(oacc[qg][dt][rp] * rcp)
                       | ((u32)f2bf(oacc[qg][dt][rp + 1] * rcp) << 16);
                *(u32*)&O[row * 1024 + h * 64 + dt * 16 + q * 4 + rp] = pk;
            }
    }
}

// V [b*2048+s][h*64+d] -> Vt [b*1024+h*64+d][s], 64x64 tiles via LDS
__global__ __launch_bounds__(256) void vtrans(const u16* __restrict__ Vb, u16* __restrict__ Vt)
{
    __shared__ __align__(16) u16 T[64 * 72];
    const int tid = threadIdx.x;
    const int ct = blockIdx.x, rt = blockIdx.y;
    const int b = rt >> 5;
    const int s0 = (rt & 31) * 64;
    const int c0 = ct * 64;
#pragma unroll
    for (int p = 0; p < 2; ++p) {
        int slot = p * 256 + tid;
        int lr = slot >> 3, pc = slot & 7;
        bf16x8 v = *(const bf16x8*)&Vb[(size_t)(b * 2048 + s0 + lr) * 1024 + c0 + pc * 8];
        *(bf16x8*)&T[lr * 72 + pc * 8] = v;
    }
    __syncthreads();
#pragma unroll
    for (int p = 0; p < 2; ++p) {
        int slot = p * 256 + tid;
        int dc = slot >> 3, sc0 = (slot & 7) * 8;
        ushort8v o;
#pragma unroll
        for (int j = 0; j < 8; ++j) o[j] = T[(sc0 + j) * 72 + dc];
        *(ushort8v*)&Vt[(size_t)(b * 1024 + c0 + dc) * 2048 + s0 + sc0] = o;
    }
}

// LayerNorm (torch semantics: ddof=1 variance, eps added to std), fp32 -> bf16
DEVI void ln_row(const float* __restrict__ x, float ga, float gb,
                 u16* __restrict__ y, int row, int tid)
{
    const float4 v = ((const float4*)(x + (size_t)row * 1024))[tid];
    float s = v.x + v.y + v.z + v.w;
    float ss = v.x * v.x + v.y * v.y + v.z * v.z + v.w * v.w;
#pragma unroll
    for (int d = 1; d < 64; d <<= 1) { s += __shfl_xor(s, d, 64); ss += __shfl_xor(ss, d, 64); }
    __shared__ float ps[4], pss[4];
    const int w = tid >> 6, lane = tid & 63;
    if (lane == 0) { ps[w] = s; pss[w] = ss; }
    __syncthreads();
    s = ps[0] + ps[1] + ps[2] + ps[3];
    ss = pss[0] + pss[1] + pss[2] + pss[3];
    float mean = s * (1.f / 1024.f);
    float var = fmaxf((ss - s * mean) * (1.f / 1023.f), 0.f);
    float sc = ga / (sqrtf(var) + 1e-6f);
    ushort4v o;
    o[0] = f2bf((v.x - mean) * sc + gb);
    o[1] = f2bf((v.y - mean) * sc + gb);
    o[2] = f2bf((v.z - mean) * sc + gb);
    o[3] = f2bf((v.w - mean) * sc + gb);
    ((ushort4v*)(y + (size_t)row * 1024))[tid] = o;
}

__global__ __launch_bounds__(256) void ln_bf16(const float* __restrict__ x,
    const float* __restrict__ ga, const float* __restrict__ gb, u16* __restrict__ y)
{
    ln_row(x, ga[0], gb[0], y, blockIdx.x, threadIdx.x);
}

// prep: weight casts (blocks 0..12287) + mask bias (12288..12303) + LN1 (12304..16399)
__global__ __launch_bounds__(256) void prep(
    const float* __restrict__ wq, const float* __restrict__ wk,
    const float* __restrict__ wv, const float* __restrict__ wo,
    const float* __restrict__ w1, const float* __restrict__ w2,
    u16* __restrict__ wqb, u16* __restrict__ wkb, u16* __restrict__ wvb,
    u16* __restrict__ wob, u16* __restrict__ w1b, u16* __restrict__ w2b,
    const int* __restrict__ m, float* __restrict__ biasv,
    const float* __restrict__ src, const float* __restrict__ a1,
    const float* __restrict__ be1, u16* __restrict__ xln1)
{
    const int bx = blockIdx.x;
    if (bx < 12288) {
        size_t i = (size_t)bx * 256 + threadIdx.x;   // float4 index
        const float* s; u16* d; size_t off;
        if (i < 262144)       { s = wq; d = wqb; off = i; }
        else if (i < 524288)  { s = wk; d = wkb; off = i - 262144; }
        else if (i < 786432)  { s = wv; d = wvb; off = i - 524288; }
        else if (i < 1048576) { s = wo; d = wob; off = i - 786432; }
        else if (i < 2097152) { s = w1; d = w1b; off = i - 1048576; }
        else                  { s = w2; d = w2b; off = i - 2097152; }
        float4 v = ((const float4*)s)[off];
        ushort4v o = {f2bf(v.x), f2bf(v.y), f2bf(v.z), f2bf(v.w)};
        ((ushort4v*)d)[off] = o;
    } else if (bx < 12304) {
        int i = (bx - 12288) * 256 + threadIdx.x;
        biasv[i] = m[i] ? 0.f : -1.442695e9f;
    } else {
        ln_row(src, a1[0], be1[0], xln1, bx - 12304, threadIdx.x);
    }
}

// FF2 finish: out = sum(bf16 partials P0..P3) + b2[col] + resid
__global__ __launch_bounds__(256) void ff2_fin(
    const u16* __restrict__ p0, const u16* __restrict__ p1,
    const u16* __restrict__ p2, const u16* __restrict__ p3,
    const float* __restrict__ b2, const float* __restrict__ resid,
    float* __restrict__ out)
{
    const size_t i = (size_t)blockIdx.x * 256 + threadIdx.x;   // float4 index
    ushort4v a = *(const ushort4v*)&p0[i * 4];
    ushort4v b = *(const ushort4v*)&p1[i * 4];
    ushort4v c = *(const ushort4v*)&p2[i * 4];
    ushort4v d = *(const ushort4v*)&p3[i * 4];
    float4 r = ((const float4*)resid)[i];
    float4 bb = ((const float4*)b2)[i & 255];
    float4 o;
    o.x = (bf2f(a[0]) + bf2f(b[0])) + (bf2f(c[0]) + bf2f(d[0])) + r.x + bb.x;
    o.y = (bf2f(a[1]) + bf2f(b[1])) + (bf2f(c[1]) + bf2f(d[1])) + r.y + bb.y;
    o.z = (bf2f(a[2]) + bf2f(b[2])) + (bf2f(c[2]) + bf2f(d[2])) + r.z + bb.z;
    o.w = (bf2f(a[3]) + bf2f(b[3])) + (bf2f(c[3]) + bf2f(d[3])) + r.w + bb.w;
    ((float4*)out)[i] = o;
}

extern "C" void kernel_launch(void* const* d_in, const int* in_sizes, int n_in,
                              void* d_out, int out_size, void* d_ws, size_t ws_size,
                              hipStream_t stream)
{
    const float* src = (const float*)d_in[0];
    const int* msk   = (const int*)d_in[1];
    const float* wq  = (const float*)d_in[2];
    const float* wk  = (const float*)d_in[3];
    const float* wv  = (const float*)d_in[4];
    const float* wo  = (const float*)d_in[5];
    const float* w1  = (const float*)d_in[6];
    const float* b1  = (const float*)d_in[7];
    const float* w2  = (const float*)d_in[8];
    const float* b2  = (const float*)d_in[9];
    const float* a1  = (const float*)d_in[10];
    const float* be1 = (const float*)d_in[11];
    const float* a2  = (const float*)d_in[12];
    const float* be2 = (const float*)d_in[13];
    float* out = (float*)d_out;

    char* ws = (char*)d_ws;
    const size_t MB = (size_t)1 << 20;
    u16* wqb  = (u16*)(ws + 0 * MB);
    u16* wkb  = (u16*)(ws + 2 * MB);
    u16* wvb  = (u16*)(ws + 4 * MB);
    u16* wob  = (u16*)(ws + 6 * MB);
    u16* w1b  = (u16*)(ws + 8 * MB);    // 8..16
    u16* w2b  = (u16*)(ws + 16 * MB);   // 16..24 (live through FF2)
    u16* xln1 = (u16*)(ws + 24 * MB);   // 24..32; dead after QKV; aliased by attn
    u16* attn = xln1;
    u16* Qb   = (u16*)(ws + 32 * MB);   // 32..40; dead after flash; aliased by xln2
    u16* xln2 = Qb;
    u16* Kb   = (u16*)(ws + 40 * MB);   // 40..48
    u16* Vb   = (u16*)(ws + 48 * MB);   // 48..56
    u16* Vt   = (u16*)(ws + 56 * MB);   // 56..64
    float* biasv = (float*)(ws + 64 * MB);  // 16 KB in 64..72 spare
    u16* h1   = (u16*)(ws + 40 * MB);   // 32 MB: 40..72 (Kb/Vb/Vt dead by then)
    float* src2 = (float*)(ws + 72 * MB); // 16 MB: 72..88
    // FF2 bf16 partials in dead regions (weights 0..16 dead, attn 24..32 dead
    // after oproj, xln2 32..40 dead after FF1):
    u16* P0 = (u16*)(ws + 0 * MB);
    u16* P1 = (u16*)(ws + 8 * MB);
    u16* P2 = (u16*)(ws + 24 * MB);
    u16* P3 = (u16*)(ws + 32 * MB);

    // fused: weight casts + mask bias + LN1
    prep<<<16400, 256, 0, stream>>>(wq, wk, wv, wo, w1, w2,
                                    wqb, wkb, wvb, wob, w1b, w2b,
                                    msk, biasv, src, a1, be1, xln1);

    // fused QKV: N_total=3072, per-block weight/output select
    gemm_nt<128, 128, 2, 2, true, 1, false, false, false, true><<<dim3(24, 32), 256, 0, stream>>>(
        xln1, wqb, wkb, wvb, nullptr, nullptr, Qb, Kb, Vb, nullptr, 1024, 1024, 1024, 0);

    vtrans<<<dim3(16, 64), 256, 0, stream>>>(Vb, Vt);

    flash7<<<dim3(32, 32), 128, 0, stream>>>(Qb, Kb, Vt, biasv, attn);

    // O-projection + residual (fp32)
    gemm_nt<128, 64, 4, 1, false, 1, false, false, true, false><<<dim3(16, 32), 256, 0, stream>>>(
        attn, wob, nullptr, nullptr, nullptr, src, src2, nullptr, nullptr, nullptr,
        1024, 1024, 1024, 0);

    ln_bf16<<<4096, 256, 0, stream>>>(src2, a2, be2, xln2);

    // FF1: bias + ReLU -> bf16
    gemm_nt<128, 128, 2, 2, false, 1, true, true, false, true><<<dim3(32, 32), 256, 0, stream>>>(
        xln2, w1b, nullptr, nullptr, b1, nullptr, h1, nullptr, nullptr, nullptr,
        1024, 1024, 4096, 0);

    // FF2: split-K=4 into bf16 partials (1024 blocks -> 4 blocks/CU)
    gemm_nt<128, 128, 2, 2, false, 4, false, false, false, true><<<dim3(32, 32), 256, 0, stream>>>(
        h1, w2b, nullptr, nullptr, nullptr, nullptr, P0, P1, P2, P3,
        1024, 4096, 1024, 8);

    // out = P0+P1+P2+P3 + b2 + src2
    ff2_fin<<<4096, 256, 0, stream>>>(P0, P1, P2, P3, b2, src2, out);
}

// Round 11
// 356.304 us; speedup vs baseline: 1.0624x; 1.0355x over previous
//
#include <hip/hip_runtime.h>
#include <hip/hip_bf16.h>

typedef unsigned short u16;
typedef unsigned int u32;
typedef float floatx4 __attribute__((ext_vector_type(4)));
typedef __bf16 bf16x8 __attribute__((ext_vector_type(8)));
typedef u16 ushort4v __attribute__((ext_vector_type(4)));
typedef u16 ushort8v __attribute__((ext_vector_type(8)));

#define DEVI static __device__ __forceinline__

DEVI u16 f2bf(float f) {
    u32 u = __builtin_bit_cast(u32, f);
    u += 0x7fffu + ((u >> 16) & 1u);   // round-to-nearest-even
    return (u16)(u >> 16);
}
DEVI float bf2f(u16 h) { return __builtin_bit_cast(float, (u32)h << 16); }

DEVI float fexp2(float x) { return __builtin_amdgcn_exp2f(x); }  // v_exp_f32

// async global->LDS, 16B per lane. dst must be wave-uniform base; HW adds lane*16.
DEVI void async_cp16(const u16* g, u16* l) {
    __builtin_amdgcn_global_load_lds((const __attribute__((address_space(1))) u32*)g,
                                     (__attribute__((address_space(3))) u32*)l, 16, 0, 0);
}

// ---------------------------------------------------------------------------
// GEMM: C[M,N] = A[M,K](bf16) @ W[N,K](bf16)^T, double-buffered one-barrier
// K-loop, async global_load_lds staging with XOR swizzle.
// XSWZ: XCD m-band block swizzle. With round-robin XCD = linearBlockId % 8,
// give each XCD a contiguous band of gy/8 m-tiles and iterate n within it:
// A-tiles become XCD-L2-local (read ~once from HBM/L3) instead of being
// duplicated across all 8 XCD L2s (R10: FF2 FETCH 139 MB from A-dup).
// NSPLIT>1: part = bx/NX works K-range [part*K, part*K+K), partials to o0..o3.
// ---------------------------------------------------------------------------
template<int BM, int BN, int RW, int CW, bool QKV3, int NSPLIT, bool XSWZ,
         bool BIAS, bool RELU, bool RESID, bool OBF16>
__global__ __launch_bounds__(256) void gemm_nt(
    const u16* __restrict__ A,
    const u16* __restrict__ W0, const u16* __restrict__ W1, const u16* __restrict__ W2,
    const float* __restrict__ bias, const float* __restrict__ resid,
    void* __restrict__ o0, void* __restrict__ o1, void* __restrict__ o2,
    void* __restrict__ o3, int K, int lda, int Nper, int NX)
{
    static_assert(RW * CW == 4, "4 waves");
    constexpr int WM = BM / RW, WN = BN / CW;
    constexpr int MI = WM / 16, NI = WN / 16;
    __shared__ __align__(16) u16 As[2][BM * 32];
    __shared__ __align__(16) u16 Bs[2][BN * 32];
    const int tid = threadIdx.x;
    const int w = tid >> 6, lane = tid & 63;
    const int q = lane >> 4, ml = lane & 15;
    const int wr = w / CW, wc = w % CW;
    int bx = blockIdx.x, by = blockIdx.y;
    if (XSWZ) {
        const int gx = gridDim.x, gy = gridDim.y;
        int L = by * gx + bx;
        int xcd = L & 7, s = L >> 3;
        int mb = gy >> 3;              // m-tiles per XCD band (gy % 8 == 0)
        by = xcd * mb + s % mb;
        bx = s / mb;
    }
    const int m0 = by * BM;
    size_t kbase = 0;
    const u16* W = W0;
    void* outp = o0;
    if (NSPLIT > 1) {
        int part = bx / NX; bx -= part * NX; kbase = (size_t)part * K;
        outp = (part == 0) ? o0 : (part == 1 ? o1 : (part == 2 ? o2 : o3));
    }
    int n0 = bx * BN;
    if (QKV3) {
        int sel = n0 / Nper;
        n0 -= sel * Nper;
        W = (sel == 0) ? W0 : (sel == 1 ? W1 : W2);
        outp = (sel == 0) ? o0 : (sel == 1 ? o1 : o2);
    }

    auto stage = [&](int buf, int kt) {
#pragma unroll
        for (int p = 0; p < BM / 64; ++p) {
            int g = p * 256 + tid;
            int r = g >> 2, s = g & 3;
            int c = s ^ ((r >> 1) & 3);
            async_cp16(A + (size_t)(m0 + r) * lda + kbase + kt + c * 8,
                       &As[buf][(p * 256 + w * 64) * 8]);
        }
#pragma unroll
        for (int p = 0; p < BN / 64; ++p) {
            int g = p * 256 + tid;
            int r = g >> 2, s = g & 3;
            int c = s ^ ((r >> 1) & 3);
            async_cp16(W + (size_t)(n0 + r) * lda + kbase + kt + c * 8,
                       &Bs[buf][(p * 256 + w * 64) * 8]);
        }
    };

    const floatx4 fzero = {0.f, 0.f, 0.f, 0.f};
    floatx4 acc[MI][NI];
#pragma unroll
    for (int i = 0; i < MI; ++i)
#pragma unroll
        for (int j = 0; j < NI; ++j) acc[i][j] = fzero;

    stage(0, 0);
    for (int it = 0, kt = 0; kt < K; ++it, kt += 32) {
        __syncthreads();
        if (kt + 32 < K) stage((it + 1) & 1, kt + 32);
        const u16* Asb = As[it & 1];
        const u16* Bsb = Bs[it & 1];
        bf16x8 af[MI], bfr[NI];
#pragma unroll
        for (int i = 0; i < MI; ++i) {
            int rm = wr * WM + i * 16 + ml;
            int s = q ^ ((rm >> 1) & 3);
            af[i] = *(const bf16x8*)&Asb[(rm * 4 + s) * 8];
        }
#pragma unroll
        for (int j = 0; j < NI; ++j) {
            int rn = wc * WN + j * 16 + ml;
            int s = q ^ ((rn >> 1) & 3);
            bfr[j] = *(const bf16x8*)&Bsb[(rn * 4 + s) * 8];
        }
#pragma unroll
        for (int i = 0; i < MI; ++i)
#pragma unroll
            for (int j = 0; j < NI; ++j)
                acc[i][j] = __builtin_amdgcn_mfma_f32_16x16x32_bf16(af[i], bfr[j], acc[i][j], 0, 0, 0);
    }

    // epilogue: C/D layout col=lane&15, row=(lane>>4)*4+reg
#pragma unroll
    for (int j = 0; j < NI; ++j) {
        int gn = n0 + wc * WN + j * 16 + ml;
        float bj = 0.f;
        if (BIAS) bj = bias[gn];
#pragma unroll
        for (int i = 0; i < MI; ++i) {
            int gm0 = m0 + wr * WM + i * 16 + q * 4;
#pragma unroll
            for (int r = 0; r < 4; ++r) {
                size_t idx = (size_t)(gm0 + r) * Nper + gn;
                float v = acc[i][j][r] + bj;
                if (RELU) v = fmaxf(v, 0.f);
                if (RESID) v += resid[idx];
                if (OBF16) ((u16*)outp)[idx] = f2bf(v);
                else       ((float*)outp)[idx] = v;
            }
        }
    }
}

// ---------------------------------------------------------------------------
// Flash attention v7 (R8 winner, unchanged): transposed-S + key-relabeled S^T
// so PV runs at 16x16x32. Block = 128 threads (2 waves) x 32 queries each.
// Zero P LDS traffic, conflict-free swizzle, per-lane lsum, 2 shuffles total.
// Q,K: [b*2048+s][h*64+d].  Vt: [b*1024+h*64+d][s].
// ---------------------------------------------------------------------------
__global__ __launch_bounds__(128, 2) void flash7(
    const u16* __restrict__ Q, const u16* __restrict__ Kg,
    const u16* __restrict__ Vt, const float* __restrict__ biasv,
    u16* __restrict__ O)
{
    __shared__ __align__(16) u16 Ks[2][64 * 64];
    __shared__ __align__(16) u16 Vs[2][64 * 64];
    const int tid = threadIdx.x;
    const int w = tid >> 6, lane = tid & 63;
    const int q = lane >> 4, ml = lane & 15;
    const int b = blockIdx.y >> 4, h = blockIdx.y & 15;
    const size_t rowQ = (size_t)(b * 2048 + blockIdx.x * 64);
    const float KSC = 0.125f * 1.4426950408889634f;   // /sqrt(64) * log2(e)
    const floatx4 fzero = {0.f, 0.f, 0.f, 0.f};

    bf16x8 qa[2][2];
#pragma unroll
    for (int qg = 0; qg < 2; ++qg)
#pragma unroll
        for (int c = 0; c < 2; ++c)
            qa[qg][c] = *(const bf16x8*)&Q[(rowQ + w * 32 + qg * 16 + ml) * 1024
                                           + h * 64 + q * 8 + c * 32];

    auto stage = [&](int buf, int s0) {
#pragma unroll
        for (int p = 0; p < 4; ++p) {
            int L = p * 128 + tid;
            int row = L >> 3, sl = L & 7;
            int ch = sl ^ ((row & 3) | (((row >> 3) & 1) << 2));
            async_cp16(Kg + (size_t)(b * 2048 + s0 + row) * 1024 + h * 64 + ch * 8,
                       &Ks[buf][(p * 128 + w * 64) * 8]);
            async_cp16(Vt + (size_t)(b * 1024 + h * 64 + row) * 2048 + s0 + ch * 8,
                       &Vs[buf][(p * 128 + w * 64) * 8]);
        }
    };

    floatx4 oacc[2][4];
    float lsum[2] = {0.f, 0.f};
#pragma unroll
    for (int qg = 0; qg < 2; ++qg)
#pragma unroll
        for (int d = 0; d < 4; ++d) oacc[qg][d] = fzero;

    const int swk = (ml & 3) | (((ml >> 2) & 1) << 2);
    const int swv = (ml & 3) | (((ml >> 3) & 1) << 2);

    stage(0, 0);
    for (int it = 0; it < 32; ++it) {
        __syncthreads();
        if (it + 1 < 32) stage((it + 1) & 1, (it + 1) * 64);
        const u16* Kb = Ks[it & 1];
        const u16* Vb = Vs[it & 1];
        const int s0 = it * 64;

        bf16x8 pfrag[2][2];   // [g][qg]
#pragma unroll
        for (int g = 0; g < 2; ++g) {
            const int re = g * 32 + ((ml >> 2) << 3) + (ml & 3);  // even rows
            bf16x8 ke0 = *(const bf16x8*)&Kb[(re + 0) * 64 + ((0 + q) ^ swk) * 8];
            bf16x8 ke1 = *(const bf16x8*)&Kb[(re + 0) * 64 + ((4 + q) ^ swk) * 8];
            bf16x8 ko0 = *(const bf16x8*)&Kb[(re + 4) * 64 + ((0 + q) ^ swk) * 8];
            bf16x8 ko1 = *(const bf16x8*)&Kb[(re + 4) * 64 + ((4 + q) ^ swk) * 8];
            const float4 be = *(const float4*)&biasv[b * 2048 + s0 + g * 32 + q * 8];
            const float4 bo = *(const float4*)&biasv[b * 2048 + s0 + g * 32 + q * 8 + 4];
#pragma unroll
            for (int qg = 0; qg < 2; ++qg) {
                floatx4 te = fzero, to = fzero;
                te = __builtin_amdgcn_mfma_f32_16x16x32_bf16(ke0, qa[qg][0], te, 0, 0, 0);
                te = __builtin_amdgcn_mfma_f32_16x16x32_bf16(ke1, qa[qg][1], te, 0, 0, 0);
                to = __builtin_amdgcn_mfma_f32_16x16x32_bf16(ko0, qa[qg][0], to, 0, 0, 0);
                to = __builtin_amdgcn_mfma_f32_16x16x32_bf16(ko1, qa[qg][1], to, 0, 0, 0);
                float pe0 = fexp2(fmaf(te[0], KSC, be.x));
                float pe1 = fexp2(fmaf(te[1], KSC, be.y));
                float pe2 = fexp2(fmaf(te[2], KSC, be.z));
                float pe3 = fexp2(fmaf(te[3], KSC, be.w));
                float po0 = fexp2(fmaf(to[0], KSC, bo.x));
                float po1 = fexp2(fmaf(to[1], KSC, bo.y));
                float po2 = fexp2(fmaf(to[2], KSC, bo.z));
                float po3 = fexp2(fmaf(to[3], KSC, bo.w));
                lsum[qg] += ((pe0 + pe1) + (pe2 + pe3)) + ((po0 + po1) + (po2 + po3));
                u32 pk[4];
                pk[0] = ((__builtin_bit_cast(u32, pe0) + 0x8000u) >> 16)
                      | ((__builtin_bit_cast(u32, pe1) + 0x8000u) & 0xffff0000u);
                pk[1] = ((__builtin_bit_cast(u32, pe2) + 0x8000u) >> 16)
                      | ((__builtin_bit_cast(u32, pe3) + 0x8000u) & 0xffff0000u);
                pk[2] = ((__builtin_bit_cast(u32, po0) + 0x8000u) >> 16)
                      | ((__builtin_bit_cast(u32, po1) + 0x8000u) & 0xffff0000u);
                pk[3] = ((__builtin_bit_cast(u32, po2) + 0x8000u) >> 16)
                      | ((__builtin_bit_cast(u32, po3) + 0x8000u) & 0xffff0000u);
                pfrag[g][qg] = __builtin_bit_cast(bf16x8, *(uint4*)pk);
            }
        }
#pragma unroll
        for (int dt = 0; dt < 4; ++dt) {
            int vrow = dt * 16 + ml;
#pragma unroll
            for (int g = 0; g < 2; ++g) {
                bf16x8 vf = *(const bf16x8*)&Vb[vrow * 64 + ((g * 4 + q) ^ swv) * 8];
#pragma unroll
                for (int qg = 0; qg < 2; ++qg)
                    oacc[qg][dt] = __builtin_amdgcn_mfma_f32_16x16x32_bf16(
                        vf, pfrag[g][qg], oacc[qg][dt], 0, 0, 0);
            }
        }
    }
#pragma unroll
    for (int qg = 0; qg < 2; ++qg) {
        float ls = lsum[qg];
        ls += __shfl_xor(ls, 16, 64);
        ls += __shfl_xor(ls, 32, 64);
        const float rcp = 1.f / ls;
        const size_t row = rowQ + w * 32 + qg * 16 + ml;
#pragma unroll
        for (int dt = 0; dt < 4; ++dt)
#pragma unroll
            for (int rp = 0; rp < 4; rp += 2) {
                u32 pk = (u32)f2bf(oacc[qg][dt][rp] * rcp)
                       | ((u32)f2bf(oacc[qg][dt][rp + 1] * rcp) << 16);
                *(u32*)&O[row * 1024 + h * 64 + dt * 16 + q * 4 + rp] = pk;
            }
    }
}

// V [b*2048+s][h*64+d] -> Vt [b*1024+h*64+d][s], 64x64 tiles via LDS
__global__ __launch_bounds__(256) void vtrans(const u16* __restrict__ Vb, u16* __restrict__ Vt)
{
    __shared__ __align__(16) u16 T[64 * 72];
    const int tid = threadIdx.x;
    const int ct = blockIdx.x, rt = blockIdx.y;
    const int b = rt >> 5;
    const int s0 = (rt & 31) * 64;
    const int c0 = ct * 64;
#pragma unroll
    for (int p = 0; p < 2; ++p) {
        int slot = p * 256 + tid;
        int lr = slot >> 3, pc = slot & 7;
        bf16x8 v = *(const bf16x8*)&Vb[(size_t)(b * 2048 + s0 + lr) * 1024 + c0 + pc * 8];
        *(bf16x8*)&T[lr * 72 + pc * 8] = v;
    }
    __syncthreads();
#pragma unroll
    for (int p = 0; p < 2; ++p) {
        int slot = p * 256 + tid;
        int dc = slot >> 3, sc0 = (slot & 7) * 8;
        ushort8v o;
#pragma unroll
        for (int j = 0; j < 8; ++j) o[j] = T[(sc0 + j) * 72 + dc];
        *(ushort8v*)&Vt[(size_t)(b * 1024 + c0 + dc) * 2048 + s0 + sc0] = o;
    }
}

// LayerNorm (torch semantics: ddof=1 variance, eps added to std), fp32 -> bf16
DEVI void ln_row(const float* __restrict__ x, float ga, float gb,
                 u16* __restrict__ y, int row, int tid)
{
    const float4 v = ((const float4*)(x + (size_t)row * 1024))[tid];
    float s = v.x + v.y + v.z + v.w;
    float ss = v.x * v.x + v.y * v.y + v.z * v.z + v.w * v.w;
#pragma unroll
    for (int d = 1; d < 64; d <<= 1) { s += __shfl_xor(s, d, 64); ss += __shfl_xor(ss, d, 64); }
    __shared__ float ps[4], pss[4];
    const int w = tid >> 6, lane = tid & 63;
    if (lane == 0) { ps[w] = s; pss[w] = ss; }
    __syncthreads();
    s = ps[0] + ps[1] + ps[2] + ps[3];
    ss = pss[0] + pss[1] + pss[2] + pss[3];
    float mean = s * (1.f / 1024.f);
    float var = fmaxf((ss - s * mean) * (1.f / 1023.f), 0.f);
    float sc = ga / (sqrtf(var) + 1e-6f);
    ushort4v o;
    o[0] = f2bf((v.x - mean) * sc + gb);
    o[1] = f2bf((v.y - mean) * sc + gb);
    o[2] = f2bf((v.z - mean) * sc + gb);
    o[3] = f2bf((v.w - mean) * sc + gb);
    ((ushort4v*)(y + (size_t)row * 1024))[tid] = o;
}

__global__ __launch_bounds__(256) void ln_bf16(const float* __restrict__ x,
    const float* __restrict__ ga, const float* __restrict__ gb, u16* __restrict__ y)
{
    ln_row(x, ga[0], gb[0], y, blockIdx.x, threadIdx.x);
}

// prep: weight casts (blocks 0..12287) + mask bias (12288..12303) + LN1 (12304..16399)
__global__ __launch_bounds__(256) void prep(
    const float* __restrict__ wq, const float* __restrict__ wk,
    const float* __restrict__ wv, const float* __restrict__ wo,
    const float* __restrict__ w1, const float* __restrict__ w2,
    u16* __restrict__ wqb, u16* __restrict__ wkb, u16* __restrict__ wvb,
    u16* __restrict__ wob, u16* __restrict__ w1b, u16* __restrict__ w2b,
    const int* __restrict__ m, float* __restrict__ biasv,
    const float* __restrict__ src, const float* __restrict__ a1,
    const float* __restrict__ be1, u16* __restrict__ xln1)
{
    const int bx = blockIdx.x;
    if (bx < 12288) {
        size_t i = (size_t)bx * 256 + threadIdx.x;   // float4 index
        const float* s; u16* d; size_t off;
        if (i < 262144)       { s = wq; d = wqb; off = i; }
        else if (i < 524288)  { s = wk; d = wkb; off = i - 262144; }
        else if (i < 786432)  { s = wv; d = wvb; off = i - 524288; }
        else if (i < 1048576) { s = wo; d = wob; off = i - 786432; }
        else if (i < 2097152) { s = w1; d = w1b; off = i - 1048576; }
        else                  { s = w2; d = w2b; off = i - 2097152; }
        float4 v = ((const float4*)s)[off];
        ushort4v o = {f2bf(v.x), f2bf(v.y), f2bf(v.z), f2bf(v.w)};
        ((ushort4v*)d)[off] = o;
    } else if (bx < 12304) {
        int i = (bx - 12288) * 256 + threadIdx.x;
        biasv[i] = m[i] ? 0.f : -1.442695e9f;
    } else {
        ln_row(src, a1[0], be1[0], xln1, bx - 12304, threadIdx.x);
    }
}

// FF2 finish: out = (bf16 partials P0+P1) + b2[col] + resid
__global__ __launch_bounds__(256) void ff2_fin(
    const u16* __restrict__ p0, const u16* __restrict__ p1,
    const float* __restrict__ b2, const float* __restrict__ resid,
    float* __restrict__ out)
{
    const size_t i = (size_t)blockIdx.x * 256 + threadIdx.x;   // float4 index
    ushort4v a = *(const ushort4v*)&p0[i * 4];
    ushort4v b = *(const ushort4v*)&p1[i * 4];
    float4 r = ((const float4*)resid)[i];
    float4 bb = ((const float4*)b2)[i & 255];
    float4 o;
    o.x = (bf2f(a[0]) + bf2f(b[0])) + r.x + bb.x;
    o.y = (bf2f(a[1]) + bf2f(b[1])) + r.y + bb.y;
    o.z = (bf2f(a[2]) + bf2f(b[2])) + r.z + bb.z;
    o.w = (bf2f(a[3]) + bf2f(b[3])) + r.w + bb.w;
    ((float4*)out)[i] = o;
}

extern "C" void kernel_launch(void* const* d_in, const int* in_sizes, int n_in,
                              void* d_out, int out_size, void* d_ws, size_t ws_size,
                              hipStream_t stream)
{
    const float* src = (const float*)d_in[0];
    const int* msk   = (const int*)d_in[1];
    const float* wq  = (const float*)d_in[2];
    const float* wk  = (const float*)d_in[3];
    const float* wv  = (const float*)d_in[4];
    const float* wo  = (const float*)d_in[5];
    const float* w1  = (const float*)d_in[6];
    const float* b1  = (const float*)d_in[7];
    const float* w2  = (const float*)d_in[8];
    const float* b2  = (const float*)d_in[9];
    const float* a1  = (const float*)d_in[10];
    const float* be1 = (const float*)d_in[11];
    const float* a2  = (const float*)d_in[12];
    const float* be2 = (const float*)d_in[13];
    float* out = (float*)d_out;

    char* ws = (char*)d_ws;
    const size_t MB = (size_t)1 << 20;
    u16* wqb  = (u16*)(ws + 0 * MB);
    u16* wkb  = (u16*)(ws + 2 * MB);
    u16* wvb  = (u16*)(ws + 4 * MB);
    u16* wob  = (u16*)(ws + 6 * MB);
    u16* w1b  = (u16*)(ws + 8 * MB);    // 8..16
    u16* w2b  = (u16*)(ws + 16 * MB);   // 16..24 (live through FF2)
    u16* xln1 = (u16*)(ws + 24 * MB);   // 24..32; dead after QKV; aliased by attn
    u16* attn = xln1;
    u16* Qb   = (u16*)(ws + 32 * MB);   // 32..40; dead after flash; aliased by xln2
    u16* xln2 = Qb;
    u16* Kb   = (u16*)(ws + 40 * MB);   // 40..48
    u16* Vb   = (u16*)(ws + 48 * MB);   // 48..56
    u16* Vt   = (u16*)(ws + 56 * MB);   // 56..64
    float* biasv = (float*)(ws + 64 * MB);  // 16 KB in 64..72 spare
    u16* h1   = (u16*)(ws + 40 * MB);   // 32 MB: 40..72 (Kb/Vb/Vt dead by then)
    float* src2 = (float*)(ws + 72 * MB); // 16 MB: 72..88
    // FF2 bf16 partials in dead regions (weights 0..8 dead, attn 24..32 dead):
    u16* P0 = (u16*)(ws + 0 * MB);
    u16* P1 = (u16*)(ws + 24 * MB);

    // fused: weight casts + mask bias + LN1
    prep<<<16400, 256, 0, stream>>>(wq, wk, wv, wo, w1, w2,
                                    wqb, wkb, wvb, wob, w1b, w2b,
                                    msk, biasv, src, a1, be1, xln1);

    // fused QKV: N_total=3072, per-block weight/output select
    gemm_nt<128, 128, 2, 2, true, 1, true, false, false, false, true><<<dim3(24, 32), 256, 0, stream>>>(
        xln1, wqb, wkb, wvb, nullptr, nullptr, Qb, Kb, Vb, nullptr, 1024, 1024, 1024, 0);

    vtrans<<<dim3(16, 64), 256, 0, stream>>>(Vb, Vt);

    flash7<<<dim3(32, 32), 128, 0, stream>>>(Qb, Kb, Vt, biasv, attn);

    // O-projection + residual (fp32)
    gemm_nt<128, 64, 4, 1, false, 1, true, false, false, true, false><<<dim3(16, 32), 256, 0, stream>>>(
        attn, wob, nullptr, nullptr, nullptr, src, src2, nullptr, nullptr, nullptr,
        1024, 1024, 1024, 0);

    ln_bf16<<<4096, 256, 0, stream>>>(src2, a2, be2, xln2);

    // FF1: bias + ReLU -> bf16
    gemm_nt<128, 128, 2, 2, false, 1, true, true, true, false, true><<<dim3(32, 32), 256, 0, stream>>>(
        xln2, w1b, nullptr, nullptr, b1, nullptr, h1, nullptr, nullptr, nullptr,
        1024, 1024, 4096, 0);

    // FF2: split-K=2 (R8-proven shape) into bf16 partials
    gemm_nt<128, 128, 2, 2, false, 2, true, false, false, false, true><<<dim3(16, 32), 256, 0, stream>>>(
        h1, w2b, nullptr, nullptr, nullptr, nullptr, P0, P1, nullptr, nullptr,
        2048, 4096, 1024, 8);

    // out = P0+P1 + b2 + src2
    ff2_fin<<<4096, 256, 0, stream>>>(P0, P1, b2, src2, out);
}